// Round 1
// baseline (726.858 us; speedup 1.0000x reference)
//
#include <hip/hip_runtime.h>
#include <cstdint>
#include <cstddef>

// Fastformer on MI355X. Pipeline:
//  1. bf16-convert Q_seq -> buf0 ; transpose-convert WQ/WK/WP (D,D)->(N,K) bf16, Wq/Wk (D,16)->(16,D) bf16
//  2. GEMM1: Qbf = Q_seq @ WQ        (128x128 tile, mfma 16x16x32 bf16, global_load_lds width=16)
//  3. GEMM2: Khbf = K_seq @ WK
//  4. q-logits: skinny MFMA GEMM (N=16) -> ql (B,H,S); softmax+pool -> gq (B,1024 flat)
//  5. QK_flat assembly (head-mixing raw reshape) -> buf0 bf16; k-logits skinny GEMM -> kl; pool*gq -> gk
//  6. Abf = Qbf * gk[b,:] ; GEMM3: out = Abf @ WP + Qbf (residual)
// Workspace: 3x32MB bf16 (Qbf,Khbf,buf0) + 6MB weights + 2.5MB logits/vecs = ~104MB.

#define B_ 8
#define S_ 2048
#define H_ 16
#define D_ 1024
#define SCALE_ 0.125f
#define BIGNEG_ 1e8f

typedef __attribute__((ext_vector_type(8))) __bf16 bf16x8;
typedef __attribute__((ext_vector_type(4))) float f32x4;

__device__ __forceinline__ unsigned short f2bf(float f) {
  unsigned int u = __float_as_uint(f);
  u += 0x7FFFu + ((u >> 16) & 1u);          // round-to-nearest-even
  return (unsigned short)(u >> 16);
}
__device__ __forceinline__ float bf2f(unsigned short h) {
  return __uint_as_float(((unsigned int)h) << 16);
}

// async global->LDS, 16B per lane (wave-uniform base + lane*16 pattern: keep lds dest linear in tid)
__device__ __forceinline__ void gll16(const void* g, void* l) {
  __builtin_amdgcn_global_load_lds(
      (__attribute__((address_space(1))) void*)(uintptr_t)g,
      (__attribute__((address_space(3))) void*)(uintptr_t)l,
      16, 0, 0);
}

// ---------------- elementwise f32 -> bf16 ----------------
__global__ __launch_bounds__(256) void k_conv(const float* __restrict__ in,
                                              unsigned short* __restrict__ out, int n4) {
  int i = blockIdx.x * 256 + threadIdx.x;
  if (i >= n4) return;
  float4 v = ((const float4*)in)[i];
  ushort4 o;
  o.x = f2bf(v.x); o.y = f2bf(v.y); o.z = f2bf(v.z); o.w = f2bf(v.w);
  ((ushort4*)out)[i] = o;
}

// ---------------- transpose + convert: src (K,N) f32 -> dst (N,K) bf16 ----------------
__global__ __launch_bounds__(256) void k_transpose_bf(const float* __restrict__ src,
                                                      unsigned short* __restrict__ dst,
                                                      int K, int N) {
  __shared__ float tile[32][33];
  int n0 = blockIdx.x * 32, k0 = blockIdx.y * 32;
  int tx = threadIdx.x, ty = threadIdx.y;  // (32,8)
#pragma unroll
  for (int i = 0; i < 4; i++) {
    int r = ty + i * 8;
    if (k0 + r < K && n0 + tx < N) tile[r][tx] = src[(size_t)(k0 + r) * N + n0 + tx];
  }
  __syncthreads();
#pragma unroll
  for (int i = 0; i < 4; i++) {
    int rn = ty + i * 8;
    if (n0 + rn < N && k0 + tx < K)
      dst[(size_t)(n0 + rn) * K + k0 + tx] = f2bf(tile[tx][rn]);
  }
}

// ---------------- 128x128 bf16 GEMM, C = A(MxK) @ BT(NxK)^T ----------------
// optional bf16 C out, optional f32 C out, optional bf16 residual add.
__global__ __launch_bounds__(256) void k_gemm128(
    const unsigned short* __restrict__ A, const unsigned short* __restrict__ BT,
    unsigned short* __restrict__ Cbf, float* __restrict__ Cf,
    const unsigned short* __restrict__ Res,
    int M, int N, int K, int ntiles) {
  __shared__ unsigned short lA[128 * 32];
  __shared__ unsigned short lB[128 * 32];
  int t = threadIdx.x;
  int mt = blockIdx.x / ntiles, nt = blockIdx.x - mt * ntiles;
  int m0 = mt * 128, n0 = nt * 128;
  int lane = t & 63, w = t >> 6;
  int wm = (w >> 1) * 64, wn = (w & 1) * 64;
  int mq = lane & 15, q = lane >> 4;

  f32x4 zero = {0.f, 0.f, 0.f, 0.f};
  f32x4 acc[4][4];
#pragma unroll
  for (int i = 0; i < 4; i++)
#pragma unroll
    for (int j = 0; j < 4; j++) acc[i][j] = zero;

  int f0 = t, f1 = t + 256;
  const unsigned short* gA0 = A + (size_t)(m0 + (f0 >> 2)) * K + (f0 & 3) * 8;
  const unsigned short* gA1 = A + (size_t)(m0 + (f1 >> 2)) * K + (f1 & 3) * 8;
  const unsigned short* gB0 = BT + (size_t)(n0 + (f0 >> 2)) * K + (f0 & 3) * 8;
  const unsigned short* gB1 = BT + (size_t)(n0 + (f1 >> 2)) * K + (f1 & 3) * 8;
  unsigned short* pA0 = &lA[f0 * 8];
  unsigned short* pA1 = &lA[f1 * 8];
  unsigned short* pB0 = &lB[f0 * 8];
  unsigned short* pB1 = &lB[f1 * 8];

  for (int k0 = 0; k0 < K; k0 += 32) {
    gll16(gA0 + k0, pA0);
    gll16(gA1 + k0, pA1);
    gll16(gB0 + k0, pB0);
    gll16(gB1 + k0, pB1);
    __syncthreads();
    bf16x8 av[4], bv[4];
#pragma unroll
    for (int i = 0; i < 4; i++)
      av[i] = *(const bf16x8*)&lA[(wm + i * 16 + mq) * 32 + q * 8];
#pragma unroll
    for (int i = 0; i < 4; i++)
      bv[i] = *(const bf16x8*)&lB[(wn + i * 16 + mq) * 32 + q * 8];
#pragma unroll
    for (int i = 0; i < 4; i++)
#pragma unroll
      for (int j = 0; j < 4; j++)
        acc[i][j] = __builtin_amdgcn_mfma_f32_16x16x32_bf16(av[i], bv[j], acc[i][j], 0, 0, 0);
    __syncthreads();
  }

#pragma unroll
  for (int i = 0; i < 4; i++)
#pragma unroll
    for (int j = 0; j < 4; j++)
#pragma unroll
      for (int r = 0; r < 4; r++) {
        int row = m0 + wm + i * 16 + q * 4 + r;
        int col = n0 + wn + j * 16 + mq;
        size_t o = (size_t)row * N + col;
        float v = acc[i][j][r];
        if (Res) v += bf2f(Res[o]);
        if (Cf) Cf[o] = v;
        if (Cbf) Cbf[o] = f2bf(v);
      }
}

// ---------------- skinny GEMM N=16: logits (B,H,S) with scale+mask ----------------
__global__ __launch_bounds__(256) void k_logits16(
    const unsigned short* __restrict__ A,      // (M=B*S, K) bf16
    const unsigned short* __restrict__ BT16,   // (16, K) bf16
    const float* __restrict__ mask,            // (B*S) f32
    float* __restrict__ outl,                  // (B,16,S) f32
    int K) {
  __shared__ unsigned short lA[128 * 32];
  int t = threadIdx.x;
  int m0 = blockIdx.x * 128;
  int lane = t & 63, w = t >> 6;
  int mq = lane & 15, q = lane >> 4;
  f32x4 zero = {0.f, 0.f, 0.f, 0.f};
  f32x4 acc0 = zero, acc1 = zero;
  int f0 = t, f1 = t + 256;
  const unsigned short* gA0 = A + (size_t)(m0 + (f0 >> 2)) * K + (f0 & 3) * 8;
  const unsigned short* gA1 = A + (size_t)(m0 + (f1 >> 2)) * K + (f1 & 3) * 8;
  unsigned short* pA0 = &lA[f0 * 8];
  unsigned short* pA1 = &lA[f1 * 8];
  for (int k0 = 0; k0 < K; k0 += 32) {
    gll16(gA0 + k0, pA0);
    gll16(gA1 + k0, pA1);
    bf16x8 bv = *(const bf16x8*)&BT16[(size_t)mq * K + k0 + q * 8];
    __syncthreads();
    bf16x8 a0 = *(const bf16x8*)&lA[(w * 32 + mq) * 32 + q * 8];
    bf16x8 a1 = *(const bf16x8*)&lA[(w * 32 + 16 + mq) * 32 + q * 8];
    acc0 = __builtin_amdgcn_mfma_f32_16x16x32_bf16(a0, bv, acc0, 0, 0, 0);
    acc1 = __builtin_amdgcn_mfma_f32_16x16x32_bf16(a1, bv, acc1, 0, 0, 0);
    __syncthreads();
  }
#pragma unroll
  for (int im = 0; im < 2; im++)
#pragma unroll
    for (int r = 0; r < 4; r++) {
      int row = m0 + w * 32 + im * 16 + q * 4 + r;
      int b = row >> 11, s = row & 2047;
      float v = (im == 0 ? acc0[r] : acc1[r]) * SCALE_ - (1.0f - mask[row]) * BIGNEG_;
      outl[((size_t)(b * 16 + mq)) * 2048 + s] = v;
    }
}

// ---------------- softmax over S + weighted pool of X columns ----------------
// out[b,1024 flat] = (sum_s softmax(logits[b,h,s]) * X[b,s,h*64+dh]) * (gmul ? gmul : 1)
__global__ __launch_bounds__(256) void k_pool(
    const float* __restrict__ logits,          // (B,16,S)
    const unsigned short* __restrict__ Xbf,    // (B,S,1024) bf16
    const float* __restrict__ gmul,            // null or (B,1024)
    float* __restrict__ outp) {                // (B,1024)
  __shared__ float sl[2048];
  __shared__ float red[16];
  __shared__ float part[4][64];
  int t = threadIdx.x;
  int bh = blockIdx.x, b = bh >> 4, h = bh & 15;
  int lane = t & 63, w = t >> 6;
  const float* lg = logits + (size_t)bh * 2048;
  float mx = -3.4e38f;
  for (int s = t; s < 2048; s += 256) { float v = lg[s]; sl[s] = v; mx = fmaxf(mx, v); }
#pragma unroll
  for (int off = 32; off > 0; off >>= 1) mx = fmaxf(mx, __shfl_down(mx, off, 64));
  if (lane == 0) red[w] = mx;
  __syncthreads();
  mx = fmaxf(fmaxf(red[0], red[1]), fmaxf(red[2], red[3]));
  float ps = 0.f;
  for (int s = t; s < 2048; s += 256) { float e = expf(sl[s] - mx); sl[s] = e; ps += e; }
#pragma unroll
  for (int off = 32; off > 0; off >>= 1) ps += __shfl_down(ps, off, 64);
  if (lane == 0) red[8 + w] = ps;
  __syncthreads();
  float denom = red[8] + red[9] + red[10] + red[11];
  float acc = 0.f;
  const unsigned short* xp = Xbf + (size_t)b * 2048 * 1024 + h * 64 + lane;
  for (int s = w; s < 2048; s += 4) acc += sl[s] * bf2f(xp[(size_t)s * 1024]);
  part[w][lane] = acc;
  __syncthreads();
  if (t < 64) {
    float tot = part[0][t] + part[1][t] + part[2][t] + part[3][t];
    float v = tot / denom;
    size_t oi = (size_t)b * 1024 + h * 64 + t;
    if (gmul) v *= gmul[oi];
    outp[oi] = v;
  }
}

// ---------------- QK_flat assembly: head-mixing raw reshape, bf16 out ----------------
__global__ __launch_bounds__(256) void k_qkflat(
    const unsigned short* __restrict__ Khbf,  // (B,S,1024)
    const float* __restrict__ gq,             // (B,1024)
    unsigned short* __restrict__ outb) {      // (B,S,1024) = QK_flat
  size_t i = (size_t)blockIdx.x * 256 + threadIdx.x;
  size_t flat = i * 4;
  int b = (int)(flat >> 21);
  int rem = (int)(flat & 2097151u);
  int sp = rem >> 10;        // s'
  int dp = rem & 1023;       // d' (multiple of 4)
  int h2 = sp >> 7;
  int j = dp >> 6;
  int dh = dp & 63;
  size_t src = ((size_t)b * 2048 + ((sp & 127) << 4) + j) * 1024 + h2 * 64 + dh;
  ushort4 kv = *(const ushort4*)&Khbf[src];
  const float* g = &gq[(size_t)b * 1024 + h2 * 64 + dh];
  ushort4 o;
  o.x = f2bf(bf2f(kv.x) * g[0]);
  o.y = f2bf(bf2f(kv.y) * g[1]);
  o.z = f2bf(bf2f(kv.z) * g[2]);
  o.w = f2bf(bf2f(kv.w) * g[3]);
  *(ushort4*)&outb[flat] = o;
}

// ---------------- A-scaling for final GEMM: Abf = Qbf * gk[b,:] ----------------
__global__ __launch_bounds__(256) void k_scaleA(
    const unsigned short* __restrict__ Qbf,
    const float* __restrict__ gk,             // (B,1024)
    unsigned short* __restrict__ outb) {
  size_t i = (size_t)blockIdx.x * 256 + threadIdx.x;
  size_t flat = i * 4;
  int b = (int)(flat >> 21);
  int d = (int)(flat & 1023);
  ushort4 qv = *(const ushort4*)&Qbf[flat];
  const float* g = &gk[(size_t)b * 1024 + d];
  ushort4 o;
  o.x = f2bf(bf2f(qv.x) * g[0]);
  o.y = f2bf(bf2f(qv.y) * g[1]);
  o.z = f2bf(bf2f(qv.z) * g[2]);
  o.w = f2bf(bf2f(qv.w) * g[3]);
  *(ushort4*)&outb[flat] = o;
}

extern "C" void kernel_launch(void* const* d_in, const int* in_sizes, int n_in,
                              void* d_out, int out_size, void* d_ws, size_t ws_size,
                              hipStream_t stream) {
  const float* Qseq  = (const float*)d_in[0];
  const float* Kseq  = (const float*)d_in[1];
  const float* Qmask = (const float*)d_in[2];
  const float* Kmask = (const float*)d_in[3];
  const float* WQ    = (const float*)d_in[4];
  const float* WK    = (const float*)d_in[5];
  const float* Wq    = (const float*)d_in[6];
  const float* Wk    = (const float*)d_in[7];
  const float* WP    = (const float*)d_in[8];
  float* out = (float*)d_out;

  const size_t SD = (size_t)B_ * S_ * D_;  // 16,777,216
  unsigned short* Qbf  = (unsigned short*)d_ws;
  unsigned short* Khbf = Qbf + SD;
  unsigned short* buf0 = Khbf + SD;           // Qseq_bf / Kseq_bf / QKflat_bf / Abf (serial reuse)
  unsigned short* WQT  = buf0 + SD;
  unsigned short* WKT  = WQT + (size_t)D_ * D_;
  unsigned short* WPT  = WKT + (size_t)D_ * D_;
  unsigned short* WqT  = WPT + (size_t)D_ * D_;
  unsigned short* WkT  = WqT + (size_t)H_ * D_;
  float* ql = (float*)(WkT + (size_t)H_ * D_);
  float* kl = ql + (size_t)B_ * H_ * S_;
  float* gq = kl + (size_t)B_ * H_ * S_;
  float* gk = gq + (size_t)B_ * D_;

  dim3 blk256(256);
  dim3 tblk(32, 8);
  int n4 = (int)(SD / 4);
  dim3 convGrid((n4 + 255) / 256);
  const int M = B_ * S_;  // 16384

  // weight conversions (transposed to N-major for B^T GEMM reads)
  k_transpose_bf<<<dim3(32, 32), tblk, 0, stream>>>(WQ, WQT, D_, D_);
  k_transpose_bf<<<dim3(32, 32), tblk, 0, stream>>>(WK, WKT, D_, D_);
  k_transpose_bf<<<dim3(32, 32), tblk, 0, stream>>>(WP, WPT, D_, D_);
  k_transpose_bf<<<dim3(1, 32), tblk, 0, stream>>>(Wq, WqT, D_, H_);
  k_transpose_bf<<<dim3(1, 32), tblk, 0, stream>>>(Wk, WkT, D_, H_);

  // GEMM1: Qbf = Q_seq @ WQ
  k_conv<<<convGrid, blk256, 0, stream>>>(Qseq, buf0, n4);
  k_gemm128<<<dim3(1024), blk256, 0, stream>>>(buf0, WQT, Qbf, (float*)nullptr,
                                               (const unsigned short*)nullptr, M, D_, D_, 8);
  // GEMM2: Khbf = K_seq @ WK
  k_conv<<<convGrid, blk256, 0, stream>>>(Kseq, buf0, n4);
  k_gemm128<<<dim3(1024), blk256, 0, stream>>>(buf0, WKT, Khbf, (float*)nullptr,
                                               (const unsigned short*)nullptr, M, D_, D_, 8);

  // q attention -> gq
  k_logits16<<<dim3(128), blk256, 0, stream>>>(Qbf, WqT, Qmask, ql, D_);
  k_pool<<<dim3(128), blk256, 0, stream>>>(ql, Qbf, (const float*)nullptr, gq);

  // k attention (over head-mixed QK_flat) -> gk
  k_qkflat<<<convGrid, blk256, 0, stream>>>(Khbf, gq, buf0);
  k_logits16<<<dim3(128), blk256, 0, stream>>>(buf0, WkT, Kmask, kl, D_);
  k_pool<<<dim3(128), blk256, 0, stream>>>(kl, Khbf, gq, gk);

  // final: out = (gk ⊙ Q) @ WP + Q
  k_scaleA<<<convGrid, blk256, 0, stream>>>(Qbf, gk, buf0);
  k_gemm128<<<dim3(1024), blk256, 0, stream>>>(buf0, WPT, (unsigned short*)nullptr, out, Qbf,
                                               M, D_, D_, 8);
}

// Round 2
// 500.470 us; speedup vs baseline: 1.4524x; 1.4524x over previous
//
#include <hip/hip_runtime.h>
#include <cstdint>
#include <cstddef>

// Fastformer on MI355X. Pipeline:
//  1. bf16-convert Q_seq -> buf0 ; transpose-convert WQ/WK/WP (D,D)->(N,K) bf16, Wq/Wk (D,16)->(16,D) bf16
//  2. GEMM1: Qbf = Q_seq @ WQ        (128x128 tile, mfma 16x16x32 bf16, global_load_lds width=16)
//  3. GEMM2: Khbf = K_seq @ WK
//  4. q-logits: skinny MFMA GEMM (N=16) -> ql; softmax in-place; chunked pool -> gq
//  5. QK_flat assembly -> buf0 bf16; k-logits -> kl; softmax; chunked pool*gq -> gk
//  6. Abf = Qbf * gk[b,:] ; GEMM3: out = Abf @ WP + Qbf (residual)
// R1 change: k_pool (130us, 1.7% HBM, 128 blocks latency-bound) split into
// k_softmax + k_poolpart (512 blocks, coalesced ushort4 X loads) + k_poolfin.

#define B_ 8
#define S_ 2048
#define H_ 16
#define D_ 1024
#define SCALE_ 0.125f
#define BIGNEG_ 1e8f

typedef __attribute__((ext_vector_type(8))) __bf16 bf16x8;
typedef __attribute__((ext_vector_type(4))) float f32x4;

__device__ __forceinline__ unsigned short f2bf(float f) {
  unsigned int u = __float_as_uint(f);
  u += 0x7FFFu + ((u >> 16) & 1u);          // round-to-nearest-even
  return (unsigned short)(u >> 16);
}
__device__ __forceinline__ float bf2f(unsigned short h) {
  return __uint_as_float(((unsigned int)h) << 16);
}

// async global->LDS, 16B per lane (wave-uniform base + lane*16 pattern: keep lds dest linear in tid)
__device__ __forceinline__ void gll16(const void* g, void* l) {
  __builtin_amdgcn_global_load_lds(
      (__attribute__((address_space(1))) void*)(uintptr_t)g,
      (__attribute__((address_space(3))) void*)(uintptr_t)l,
      16, 0, 0);
}

// ---------------- elementwise f32 -> bf16 ----------------
__global__ __launch_bounds__(256) void k_conv(const float* __restrict__ in,
                                              unsigned short* __restrict__ out, int n4) {
  int i = blockIdx.x * 256 + threadIdx.x;
  if (i >= n4) return;
  float4 v = ((const float4*)in)[i];
  ushort4 o;
  o.x = f2bf(v.x); o.y = f2bf(v.y); o.z = f2bf(v.z); o.w = f2bf(v.w);
  ((ushort4*)out)[i] = o;
}

// ---------------- transpose + convert: src (K,N) f32 -> dst (N,K) bf16 ----------------
__global__ __launch_bounds__(256) void k_transpose_bf(const float* __restrict__ src,
                                                      unsigned short* __restrict__ dst,
                                                      int K, int N) {
  __shared__ float tile[32][33];
  int n0 = blockIdx.x * 32, k0 = blockIdx.y * 32;
  int tx = threadIdx.x, ty = threadIdx.y;  // (32,8)
#pragma unroll
  for (int i = 0; i < 4; i++) {
    int r = ty + i * 8;
    if (k0 + r < K && n0 + tx < N) tile[r][tx] = src[(size_t)(k0 + r) * N + n0 + tx];
  }
  __syncthreads();
#pragma unroll
  for (int i = 0; i < 4; i++) {
    int rn = ty + i * 8;
    if (n0 + rn < N && k0 + tx < K)
      dst[(size_t)(n0 + rn) * K + k0 + tx] = f2bf(tile[tx][rn]);
  }
}

// ---------------- 128x128 bf16 GEMM, C = A(MxK) @ BT(NxK)^T ----------------
__global__ __launch_bounds__(256) void k_gemm128(
    const unsigned short* __restrict__ A, const unsigned short* __restrict__ BT,
    unsigned short* __restrict__ Cbf, float* __restrict__ Cf,
    const unsigned short* __restrict__ Res,
    int M, int N, int K, int ntiles) {
  __shared__ unsigned short lA[128 * 32];
  __shared__ unsigned short lB[128 * 32];
  int t = threadIdx.x;
  int mt = blockIdx.x / ntiles, nt = blockIdx.x - mt * ntiles;
  int m0 = mt * 128, n0 = nt * 128;
  int lane = t & 63, w = t >> 6;
  int wm = (w >> 1) * 64, wn = (w & 1) * 64;
  int mq = lane & 15, q = lane >> 4;

  f32x4 zero = {0.f, 0.f, 0.f, 0.f};
  f32x4 acc[4][4];
#pragma unroll
  for (int i = 0; i < 4; i++)
#pragma unroll
    for (int j = 0; j < 4; j++) acc[i][j] = zero;

  int f0 = t, f1 = t + 256;
  const unsigned short* gA0 = A + (size_t)(m0 + (f0 >> 2)) * K + (f0 & 3) * 8;
  const unsigned short* gA1 = A + (size_t)(m0 + (f1 >> 2)) * K + (f1 & 3) * 8;
  const unsigned short* gB0 = BT + (size_t)(n0 + (f0 >> 2)) * K + (f0 & 3) * 8;
  const unsigned short* gB1 = BT + (size_t)(n0 + (f1 >> 2)) * K + (f1 & 3) * 8;
  unsigned short* pA0 = &lA[f0 * 8];
  unsigned short* pA1 = &lA[f1 * 8];
  unsigned short* pB0 = &lB[f0 * 8];
  unsigned short* pB1 = &lB[f1 * 8];

  for (int k0 = 0; k0 < K; k0 += 32) {
    gll16(gA0 + k0, pA0);
    gll16(gA1 + k0, pA1);
    gll16(gB0 + k0, pB0);
    gll16(gB1 + k0, pB1);
    __syncthreads();
    bf16x8 av[4], bv[4];
#pragma unroll
    for (int i = 0; i < 4; i++)
      av[i] = *(const bf16x8*)&lA[(wm + i * 16 + mq) * 32 + q * 8];
#pragma unroll
    for (int i = 0; i < 4; i++)
      bv[i] = *(const bf16x8*)&lB[(wn + i * 16 + mq) * 32 + q * 8];
#pragma unroll
    for (int i = 0; i < 4; i++)
#pragma unroll
      for (int j = 0; j < 4; j++)
        acc[i][j] = __builtin_amdgcn_mfma_f32_16x16x32_bf16(av[i], bv[j], acc[i][j], 0, 0, 0);
    __syncthreads();
  }

#pragma unroll
  for (int i = 0; i < 4; i++)
#pragma unroll
    for (int j = 0; j < 4; j++)
#pragma unroll
      for (int r = 0; r < 4; r++) {
        int row = m0 + wm + i * 16 + q * 4 + r;
        int col = n0 + wn + j * 16 + mq;
        size_t o = (size_t)row * N + col;
        float v = acc[i][j][r];
        if (Res) v += bf2f(Res[o]);
        if (Cf) Cf[o] = v;
        if (Cbf) Cbf[o] = f2bf(v);
      }
}

// ---------------- skinny GEMM N=16: logits (B,H,S) with scale+mask ----------------
__global__ __launch_bounds__(256) void k_logits16(
    const unsigned short* __restrict__ A,      // (M=B*S, K) bf16
    const unsigned short* __restrict__ BT16,   // (16, K) bf16
    const float* __restrict__ mask,            // (B*S) f32
    float* __restrict__ outl,                  // (B,16,S) f32
    int K) {
  __shared__ unsigned short lA[128 * 32];
  int t = threadIdx.x;
  int m0 = blockIdx.x * 128;
  int lane = t & 63, w = t >> 6;
  int mq = lane & 15, q = lane >> 4;
  f32x4 zero = {0.f, 0.f, 0.f, 0.f};
  f32x4 acc0 = zero, acc1 = zero;
  int f0 = t, f1 = t + 256;
  const unsigned short* gA0 = A + (size_t)(m0 + (f0 >> 2)) * K + (f0 & 3) * 8;
  const unsigned short* gA1 = A + (size_t)(m0 + (f1 >> 2)) * K + (f1 & 3) * 8;
  unsigned short* pA0 = &lA[f0 * 8];
  unsigned short* pA1 = &lA[f1 * 8];
  for (int k0 = 0; k0 < K; k0 += 32) {
    gll16(gA0 + k0, pA0);
    gll16(gA1 + k0, pA1);
    bf16x8 bv = *(const bf16x8*)&BT16[(size_t)mq * K + k0 + q * 8];
    __syncthreads();
    bf16x8 a0 = *(const bf16x8*)&lA[(w * 32 + mq) * 32 + q * 8];
    bf16x8 a1 = *(const bf16x8*)&lA[(w * 32 + 16 + mq) * 32 + q * 8];
    acc0 = __builtin_amdgcn_mfma_f32_16x16x32_bf16(a0, bv, acc0, 0, 0, 0);
    acc1 = __builtin_amdgcn_mfma_f32_16x16x32_bf16(a1, bv, acc1, 0, 0, 0);
    __syncthreads();
  }
#pragma unroll
  for (int im = 0; im < 2; im++)
#pragma unroll
    for (int r = 0; r < 4; r++) {
      int row = m0 + w * 32 + im * 16 + q * 4 + r;
      int b = row >> 11, s = row & 2047;
      float v = (im == 0 ? acc0[r] : acc1[r]) * SCALE_ - (1.0f - mask[row]) * BIGNEG_;
      outl[((size_t)(b * 16 + mq)) * 2048 + s] = v;
    }
}

// ---------------- in-place softmax over rows of 2048 ----------------
__global__ __launch_bounds__(256) void k_softmax(float* __restrict__ logits) {
  __shared__ float red[8];
  int t = threadIdx.x;
  int lane = t & 63, w = t >> 6;
  float* lg = logits + (size_t)blockIdx.x * 2048;
  float4 a = ((const float4*)lg)[t];
  float4 b = ((const float4*)lg)[t + 256];
  float mx = fmaxf(fmaxf(fmaxf(a.x, a.y), fmaxf(a.z, a.w)),
                   fmaxf(fmaxf(b.x, b.y), fmaxf(b.z, b.w)));
#pragma unroll
  for (int off = 32; off > 0; off >>= 1) mx = fmaxf(mx, __shfl_down(mx, off, 64));
  if (lane == 0) red[w] = mx;
  __syncthreads();
  mx = fmaxf(fmaxf(red[0], red[1]), fmaxf(red[2], red[3]));
  float4 ea, eb;
  ea.x = expf(a.x - mx); ea.y = expf(a.y - mx); ea.z = expf(a.z - mx); ea.w = expf(a.w - mx);
  eb.x = expf(b.x - mx); eb.y = expf(b.y - mx); eb.z = expf(b.z - mx); eb.w = expf(b.w - mx);
  float ps = ea.x + ea.y + ea.z + ea.w + eb.x + eb.y + eb.z + eb.w;
#pragma unroll
  for (int off = 32; off > 0; off >>= 1) ps += __shfl_down(ps, off, 64);
  if (lane == 0) red[4 + w] = ps;
  __syncthreads();
  float inv = 1.0f / (red[4] + red[5] + red[6] + red[7]);
  ea.x *= inv; ea.y *= inv; ea.z *= inv; ea.w *= inv;
  eb.x *= inv; eb.y *= inv; eb.z *= inv; eb.w *= inv;
  ((float4*)lg)[t] = ea;
  ((float4*)lg)[t + 256] = eb;
}

// ---------------- chunked weighted pool, stage 1 ----------------
// partial[(b*64+c)*1024 + d] = sum_{s in chunk c} att[b,h(d),s] * X[b,s,d]
__global__ __launch_bounds__(256) void k_poolpart(
    const float* __restrict__ att,             // (B,16,2048) softmaxed
    const unsigned short* __restrict__ X,      // (B,2048,1024) bf16
    float* __restrict__ partial) {             // (B,64,1024) f32
  __shared__ float satt[32 * 16];
  int c = blockIdx.x, b = blockIdx.y;
  int t = threadIdx.x;
  for (int i = t; i < 512; i += 256) {
    int sl = i >> 4, h = i & 15;
    satt[i] = att[(((size_t)b * 16 + h) << 11) + c * 32 + sl];
  }
  __syncthreads();
  int h = t >> 4;  // head of d = 4t  (d>>6 == t>>4)
  const ushort4* xp = (const ushort4*)X + ((size_t)b * 2048 + c * 32) * 256 + t;
  float4 acc = {0.f, 0.f, 0.f, 0.f};
#pragma unroll 8
  for (int sl = 0; sl < 32; sl++) {
    float av = satt[sl * 16 + h];
    ushort4 xv = xp[sl * 256];
    acc.x += av * bf2f(xv.x);
    acc.y += av * bf2f(xv.y);
    acc.z += av * bf2f(xv.z);
    acc.w += av * bf2f(xv.w);
  }
  ((float4*)partial)[((size_t)b * 64 + c) * 256 + t] = acc;
}

// ---------------- chunked weighted pool, stage 2 ----------------
__global__ __launch_bounds__(256) void k_poolfin(
    const float* __restrict__ partial,         // (B,64,1024)
    const float* __restrict__ gmul,            // null or (B,1024)
    float* __restrict__ outp) {                // (B,1024)
  int oi = blockIdx.x * 256 + threadIdx.x;     // 0..8191
  int b = oi >> 10, d = oi & 1023;
  const float* pp = partial + (size_t)b * 64 * 1024 + d;
  float s = 0.f;
#pragma unroll 8
  for (int c = 0; c < 64; c++) s += pp[(size_t)c * 1024];
  if (gmul) s *= gmul[oi];
  outp[oi] = s;
}

// ---------------- QK_flat assembly: head-mixing raw reshape, bf16 out ----------------
__global__ __launch_bounds__(256) void k_qkflat(
    const unsigned short* __restrict__ Khbf,  // (B,S,1024)
    const float* __restrict__ gq,             // (B,1024)
    unsigned short* __restrict__ outb) {      // (B,S,1024) = QK_flat
  size_t i = (size_t)blockIdx.x * 256 + threadIdx.x;
  size_t flat = i * 4;
  int b = (int)(flat >> 21);
  int rem = (int)(flat & 2097151u);
  int sp = rem >> 10;        // s'
  int dp = rem & 1023;       // d' (multiple of 4)
  int h2 = sp >> 7;
  int j = dp >> 6;
  int dh = dp & 63;
  size_t src = ((size_t)b * 2048 + ((sp & 127) << 4) + j) * 1024 + h2 * 64 + dh;
  ushort4 kv = *(const ushort4*)&Khbf[src];
  const float* g = &gq[(size_t)b * 1024 + h2 * 64 + dh];
  ushort4 o;
  o.x = f2bf(bf2f(kv.x) * g[0]);
  o.y = f2bf(bf2f(kv.y) * g[1]);
  o.z = f2bf(bf2f(kv.z) * g[2]);
  o.w = f2bf(bf2f(kv.w) * g[3]);
  *(ushort4*)&outb[flat] = o;
}

// ---------------- A-scaling for final GEMM: Abf = Qbf * gk[b,:] ----------------
__global__ __launch_bounds__(256) void k_scaleA(
    const unsigned short* __restrict__ Qbf,
    const float* __restrict__ gk,             // (B,1024)
    unsigned short* __restrict__ outb) {
  size_t i = (size_t)blockIdx.x * 256 + threadIdx.x;
  size_t flat = i * 4;
  int b = (int)(flat >> 21);
  int d = (int)(flat & 1023);
  ushort4 qv = *(const ushort4*)&Qbf[flat];
  const float* g = &gk[(size_t)b * 1024 + d];
  ushort4 o;
  o.x = f2bf(bf2f(qv.x) * g[0]);
  o.y = f2bf(bf2f(qv.y) * g[1]);
  o.z = f2bf(bf2f(qv.z) * g[2]);
  o.w = f2bf(bf2f(qv.w) * g[3]);
  *(ushort4*)&outb[flat] = o;
}

extern "C" void kernel_launch(void* const* d_in, const int* in_sizes, int n_in,
                              void* d_out, int out_size, void* d_ws, size_t ws_size,
                              hipStream_t stream) {
  const float* Qseq  = (const float*)d_in[0];
  const float* Kseq  = (const float*)d_in[1];
  const float* Qmask = (const float*)d_in[2];
  const float* Kmask = (const float*)d_in[3];
  const float* WQ    = (const float*)d_in[4];
  const float* WK    = (const float*)d_in[5];
  const float* Wq    = (const float*)d_in[6];
  const float* Wk    = (const float*)d_in[7];
  const float* WP    = (const float*)d_in[8];
  float* out = (float*)d_out;

  const size_t SD = (size_t)B_ * S_ * D_;  // 16,777,216
  unsigned short* Qbf  = (unsigned short*)d_ws;
  unsigned short* Khbf = Qbf + SD;
  unsigned short* buf0 = Khbf + SD;           // staging / QKflat / Abf / pool partials (serial reuse)
  unsigned short* WQT  = buf0 + SD;
  unsigned short* WKT  = WQT + (size_t)D_ * D_;
  unsigned short* WPT  = WKT + (size_t)D_ * D_;
  unsigned short* WqT  = WPT + (size_t)D_ * D_;
  unsigned short* WkT  = WqT + (size_t)H_ * D_;
  float* ql = (float*)(WkT + (size_t)H_ * D_);
  float* kl = ql + (size_t)B_ * H_ * S_;
  float* gq = kl + (size_t)B_ * H_ * S_;
  float* gk = gq + (size_t)B_ * D_;
  float* partial = (float*)buf0;              // (B,64,1024) f32 = 2 MB, reused window

  dim3 blk256(256);
  dim3 tblk(32, 8);
  int n4 = (int)(SD / 4);
  dim3 convGrid((n4 + 255) / 256);
  const int M = B_ * S_;  // 16384

  // weight conversions (transposed to N-major for B^T GEMM reads)
  k_transpose_bf<<<dim3(32, 32), tblk, 0, stream>>>(WQ, WQT, D_, D_);
  k_transpose_bf<<<dim3(32, 32), tblk, 0, stream>>>(WK, WKT, D_, D_);
  k_transpose_bf<<<dim3(32, 32), tblk, 0, stream>>>(WP, WPT, D_, D_);
  k_transpose_bf<<<dim3(1, 32), tblk, 0, stream>>>(Wq, WqT, D_, H_);
  k_transpose_bf<<<dim3(1, 32), tblk, 0, stream>>>(Wk, WkT, D_, H_);

  // GEMM1: Qbf = Q_seq @ WQ
  k_conv<<<convGrid, blk256, 0, stream>>>(Qseq, buf0, n4);
  k_gemm128<<<dim3(1024), blk256, 0, stream>>>(buf0, WQT, Qbf, (float*)nullptr,
                                               (const unsigned short*)nullptr, M, D_, D_, 8);
  // GEMM2: Khbf = K_seq @ WK
  k_conv<<<convGrid, blk256, 0, stream>>>(Kseq, buf0, n4);
  k_gemm128<<<dim3(1024), blk256, 0, stream>>>(buf0, WKT, Khbf, (float*)nullptr,
                                               (const unsigned short*)nullptr, M, D_, D_, 8);

  // q attention -> gq
  k_logits16<<<dim3(128), blk256, 0, stream>>>(Qbf, WqT, Qmask, ql, D_);
  k_softmax<<<dim3(128), blk256, 0, stream>>>(ql);
  k_poolpart<<<dim3(64, 8), blk256, 0, stream>>>(ql, Qbf, partial);
  k_poolfin<<<dim3(32), blk256, 0, stream>>>(partial, (const float*)nullptr, gq);

  // k attention (over head-mixed QK_flat) -> gk
  k_qkflat<<<convGrid, blk256, 0, stream>>>(Khbf, gq, buf0);
  k_logits16<<<dim3(128), blk256, 0, stream>>>(buf0, WkT, Kmask, kl, D_);
  k_softmax<<<dim3(128), blk256, 0, stream>>>(kl);
  k_poolpart<<<dim3(64, 8), blk256, 0, stream>>>(kl, Khbf, partial);
  k_poolfin<<<dim3(32), blk256, 0, stream>>>(partial, gq, gk);

  // final: out = (gk ⊙ Q) @ WP + Q
  k_scaleA<<<convGrid, blk256, 0, stream>>>(Qbf, gk, buf0);
  k_gemm128<<<dim3(1024), blk256, 0, stream>>>(buf0, WPT, (unsigned short*)nullptr, out, Qbf,
                                               M, D_, D_, 8);
}

// Round 3
// 457.598 us; speedup vs baseline: 1.5884x; 1.0937x over previous
//
#include <hip/hip_runtime.h>
#include <cstdint>
#include <cstddef>

// Fastformer on MI355X. R3 pipeline:
//  - transpose-convert weights (one z-indexed dispatch for WQ/WK/WP)
//  - GEMM1: Qbf = Q_seq @ WQ   (128x128 tile, BK=64, mfma 16x16x32 bf16, gll16 staging)
//  - GEMM2: Khbf = K_seq @ WK
//  - q-logits (N=16 MFMA) -> softmax -> chunked pool -> gq
//  - k-logits with FUSED head-mixing gather from Khbf + gq folded into B-frag (k_qkflat deleted)
//  - softmax -> chunked pool (gmul=gq) -> gk
//  - WPb[b] = WP^T * gk[b,:] along K (k_scaleA deleted); GEMM3: out = Qbf @ WPb(b) + Qbf

#define B_ 8
#define S_ 2048
#define H_ 16
#define D_ 1024
#define SCALE_ 0.125f
#define BIGNEG_ 1e8f

typedef __attribute__((ext_vector_type(8))) __bf16 bf16x8;
typedef __attribute__((ext_vector_type(4))) float f32x4;

__device__ __forceinline__ unsigned short f2bf(float f) {
  unsigned int u = __float_as_uint(f);
  u += 0x7FFFu + ((u >> 16) & 1u);          // round-to-nearest-even
  return (unsigned short)(u >> 16);
}
__device__ __forceinline__ float bf2f(unsigned short h) {
  return __uint_as_float(((unsigned int)h) << 16);
}

__device__ __forceinline__ void gll16(const void* g, void* l) {
  __builtin_amdgcn_global_load_lds(
      (__attribute__((address_space(1))) void*)(uintptr_t)g,
      (__attribute__((address_space(3))) void*)(uintptr_t)l,
      16, 0, 0);
}

// ---------------- elementwise f32 -> bf16 ----------------
__global__ __launch_bounds__(256) void k_conv(const float* __restrict__ in,
                                              unsigned short* __restrict__ out, int n4) {
  int i = blockIdx.x * 256 + threadIdx.x;
  if (i >= n4) return;
  float4 v = ((const float4*)in)[i];
  ushort4 o;
  o.x = f2bf(v.x); o.y = f2bf(v.y); o.z = f2bf(v.z); o.w = f2bf(v.w);
  ((ushort4*)out)[i] = o;
}

// ---------------- transpose + convert, z selects among 3 (K,N)->(N,K) ----------------
__global__ __launch_bounds__(256) void k_transpose3(
    const float* __restrict__ s0, unsigned short* __restrict__ d0,
    const float* __restrict__ s1, unsigned short* __restrict__ d1,
    const float* __restrict__ s2, unsigned short* __restrict__ d2,
    int K, int N) {
  const float* src = blockIdx.z == 0 ? s0 : (blockIdx.z == 1 ? s1 : s2);
  unsigned short* dst = blockIdx.z == 0 ? d0 : (blockIdx.z == 1 ? d1 : d2);
  __shared__ float tile[32][33];
  int n0 = blockIdx.x * 32, k0 = blockIdx.y * 32;
  int tx = threadIdx.x, ty = threadIdx.y;  // (32,8)
#pragma unroll
  for (int i = 0; i < 4; i++) {
    int r = ty + i * 8;
    if (k0 + r < K && n0 + tx < N) tile[r][tx] = src[(size_t)(k0 + r) * N + n0 + tx];
  }
  __syncthreads();
#pragma unroll
  for (int i = 0; i < 4; i++) {
    int rn = ty + i * 8;
    if (n0 + rn < N && k0 + tx < K)
      dst[(size_t)(n0 + rn) * K + k0 + tx] = f2bf(tile[tx][rn]);
  }
}

__global__ __launch_bounds__(256) void k_transpose2(
    const float* __restrict__ s0, unsigned short* __restrict__ d0,
    const float* __restrict__ s1, unsigned short* __restrict__ d1,
    int K, int N) {
  const float* src = blockIdx.z == 0 ? s0 : s1;
  unsigned short* dst = blockIdx.z == 0 ? d0 : d1;
  __shared__ float tile[32][33];
  int n0 = blockIdx.x * 32, k0 = blockIdx.y * 32;
  int tx = threadIdx.x, ty = threadIdx.y;
#pragma unroll
  for (int i = 0; i < 4; i++) {
    int r = ty + i * 8;
    if (k0 + r < K && n0 + tx < N) tile[r][tx] = src[(size_t)(k0 + r) * N + n0 + tx];
  }
  __syncthreads();
#pragma unroll
  for (int i = 0; i < 4; i++) {
    int rn = ty + i * 8;
    if (n0 + rn < N && k0 + tx < K)
      dst[(size_t)(n0 + rn) * K + k0 + tx] = f2bf(tile[tx][rn]);
  }
}

// ---------------- 128x128 bf16 GEMM, BK=64. C = A(MxK) @ BT^T ----------------
// BT = bstride ? BTa + (mt>>4)*bstride : (mt<split ? BTa : BTb)
__global__ __launch_bounds__(256) void k_gemm128(
    const unsigned short* __restrict__ A,
    const unsigned short* __restrict__ BTa, const unsigned short* __restrict__ BTb,
    int split, int bstride,
    unsigned short* __restrict__ Cbf, float* __restrict__ Cf,
    const unsigned short* __restrict__ Res,
    int M, int N, int K, int ntiles) {
  __shared__ unsigned short lA[128 * 64];
  __shared__ unsigned short lB[128 * 64];
  int t = threadIdx.x;
  int mt = blockIdx.x / ntiles, nt = blockIdx.x - mt * ntiles;
  int m0 = mt * 128, n0 = nt * 128;
  const unsigned short* BT =
      bstride ? (BTa + (size_t)(mt >> 4) * bstride) : (mt < split ? BTa : BTb);
  int lane = t & 63, w = t >> 6;
  int wm = (w >> 1) * 64, wn = (w & 1) * 64;
  int mq = lane & 15, q = lane >> 4;

  f32x4 zero = {0.f, 0.f, 0.f, 0.f};
  f32x4 acc[4][4];
#pragma unroll
  for (int i = 0; i < 4; i++)
#pragma unroll
    for (int j = 0; j < 4; j++) acc[i][j] = zero;

  // staging: 4 granules of 16B per thread per matrix; granule g = t + p*256,
  // row = g>>3 (8 granules per 128-byte row), chunk c = g&7
  const unsigned short* gA[4];
  const unsigned short* gB[4];
  unsigned short* pA[4];
  unsigned short* pB[4];
#pragma unroll
  for (int p = 0; p < 4; p++) {
    int g = t + p * 256;
    int row = g >> 3, c = g & 7;
    gA[p] = A + (size_t)(m0 + row) * K + c * 8;
    gB[p] = BT + (size_t)(n0 + row) * K + c * 8;
    pA[p] = &lA[g * 8];
    pB[p] = &lB[g * 8];
  }

  for (int k0 = 0; k0 < K; k0 += 64) {
#pragma unroll
    for (int p = 0; p < 4; p++) gll16(gA[p] + k0, pA[p]);
#pragma unroll
    for (int p = 0; p < 4; p++) gll16(gB[p] + k0, pB[p]);
    __syncthreads();
#pragma unroll
    for (int kk = 0; kk < 2; kk++) {
      bf16x8 av[4], bv[4];
#pragma unroll
      for (int i = 0; i < 4; i++)
        av[i] = *(const bf16x8*)&lA[(wm + i * 16 + mq) * 64 + kk * 32 + q * 8];
#pragma unroll
      for (int i = 0; i < 4; i++)
        bv[i] = *(const bf16x8*)&lB[(wn + i * 16 + mq) * 64 + kk * 32 + q * 8];
#pragma unroll
      for (int i = 0; i < 4; i++)
#pragma unroll
        for (int j = 0; j < 4; j++)
          acc[i][j] = __builtin_amdgcn_mfma_f32_16x16x32_bf16(av[i], bv[j], acc[i][j], 0, 0, 0);
    }
    __syncthreads();
  }

#pragma unroll
  for (int i = 0; i < 4; i++)
#pragma unroll
    for (int j = 0; j < 4; j++)
#pragma unroll
      for (int r = 0; r < 4; r++) {
        int row = m0 + wm + i * 16 + q * 4 + r;
        int col = n0 + wn + j * 16 + mq;
        size_t o = (size_t)row * N + col;
        float v = acc[i][j][r];
        if (Res) v += bf2f(Res[o]);
        if (Cf) Cf[o] = v;
        if (Cbf) Cbf[o] = f2bf(v);
      }
}

// ---------------- skinny GEMM N=16: logits with scale+mask ----------------
__global__ __launch_bounds__(256) void k_logits16(
    const unsigned short* __restrict__ A,      // (B*S, K) bf16
    const unsigned short* __restrict__ BT16,   // (16, K) bf16
    const float* __restrict__ mask,            // (B*S) f32
    float* __restrict__ outl,                  // (B,16,S) f32
    int K) {
  __shared__ unsigned short lA[128 * 32];
  int t = threadIdx.x;
  int m0 = blockIdx.x * 128;
  int lane = t & 63, w = t >> 6;
  int mq = lane & 15, q = lane >> 4;
  f32x4 zero = {0.f, 0.f, 0.f, 0.f};
  f32x4 acc0 = zero, acc1 = zero;
  int f0 = t, f1 = t + 256;
  const unsigned short* gA0 = A + (size_t)(m0 + (f0 >> 2)) * K + (f0 & 3) * 8;
  const unsigned short* gA1 = A + (size_t)(m0 + (f1 >> 2)) * K + (f1 & 3) * 8;
  unsigned short* pA0 = &lA[f0 * 8];
  unsigned short* pA1 = &lA[f1 * 8];
  for (int k0 = 0; k0 < K; k0 += 32) {
    gll16(gA0 + k0, pA0);
    gll16(gA1 + k0, pA1);
    bf16x8 bv = *(const bf16x8*)&BT16[(size_t)mq * K + k0 + q * 8];
    __syncthreads();
    bf16x8 a0 = *(const bf16x8*)&lA[(w * 32 + mq) * 32 + q * 8];
    bf16x8 a1 = *(const bf16x8*)&lA[(w * 32 + 16 + mq) * 32 + q * 8];
    acc0 = __builtin_amdgcn_mfma_f32_16x16x32_bf16(a0, bv, acc0, 0, 0, 0);
    acc1 = __builtin_amdgcn_mfma_f32_16x16x32_bf16(a1, bv, acc1, 0, 0, 0);
    __syncthreads();
  }
#pragma unroll
  for (int im = 0; im < 2; im++)
#pragma unroll
    for (int r = 0; r < 4; r++) {
      int row = m0 + w * 32 + im * 16 + q * 4 + r;
      int b = row >> 11, s = row & 2047;
      float v = (im == 0 ? acc0[r] : acc1[r]) * SCALE_ - (1.0f - mask[row]) * BIGNEG_;
      outl[((size_t)(b * 16 + mq)) * 2048 + s] = v;
    }
}

// ---------------- k-logits with fused head-mixing gather + gq-scaled B ----------------
// A_local[r][k] = Khbf[b, 16r + (k>>6), h2*64 + (k&63)]   (r = s'&127, h2 = s'>>7)
// logits = (A_local .* gq-row-scale) @ Wk == A_local @ (Wk .* gq[k-mapped])
__global__ __launch_bounds__(256) void k_logits16g(
    const unsigned short* __restrict__ Khbf,   // (B,2048,1024) bf16
    const unsigned short* __restrict__ WkT,    // (16,1024) bf16
    const float* __restrict__ gq,              // (B,1024) f32
    const float* __restrict__ mask,            // (B*S) f32
    float* __restrict__ outl) {                // (B,16,S) f32
  __shared__ unsigned short lA[128 * 32];
  int t = threadIdx.x;
  int m0 = blockIdx.x * 128;
  int bb = m0 >> 11, h2 = (m0 >> 7) & 15;
  int lane = t & 63, w = t >> 6;
  int mq = lane & 15, q = lane >> 4;
  f32x4 zero = {0.f, 0.f, 0.f, 0.f};
  f32x4 acc0 = zero, acc1 = zero;
  int f0 = t, f1 = t + 256;
  int r0 = f0 >> 2, c0 = f0 & 3;
  int r1 = f1 >> 2, c1 = f1 & 3;
  const unsigned short* base = Khbf + (size_t)bb * 2048 * 1024 + h2 * 64;
  const float* gqb = gq + bb * 1024 + h2 * 64;
  unsigned short* pA0 = &lA[f0 * 8];
  unsigned short* pA1 = &lA[f1 * 8];
  for (int k0 = 0; k0 < 1024; k0 += 32) {
    int kc0 = k0 + c0 * 8, kc1 = k0 + c1 * 8;
    gll16(base + (size_t)(16 * r0 + (kc0 >> 6)) * 1024 + (kc0 & 63), pA0);
    gll16(base + (size_t)(16 * r1 + (kc1 >> 6)) * 1024 + (kc1 & 63), pA1);
    // B-frag: Wk row mq, k-octet q, scaled by gq[b, h2*64 + (k&63)]
    int kq = k0 + q * 8;
    bf16x8 wv = *(const bf16x8*)&WkT[(size_t)mq * 1024 + kq];
    float4 g0 = *(const float4*)&gqb[kq & 63];
    float4 g1 = *(const float4*)&gqb[(kq & 63) + 4];
    bf16x8 bv;
    bv[0] = (__bf16)((float)wv[0] * g0.x);
    bv[1] = (__bf16)((float)wv[1] * g0.y);
    bv[2] = (__bf16)((float)wv[2] * g0.z);
    bv[3] = (__bf16)((float)wv[3] * g0.w);
    bv[4] = (__bf16)((float)wv[4] * g1.x);
    bv[5] = (__bf16)((float)wv[5] * g1.y);
    bv[6] = (__bf16)((float)wv[6] * g1.z);
    bv[7] = (__bf16)((float)wv[7] * g1.w);
    __syncthreads();
    bf16x8 a0 = *(const bf16x8*)&lA[(w * 32 + mq) * 32 + q * 8];
    bf16x8 a1 = *(const bf16x8*)&lA[(w * 32 + 16 + mq) * 32 + q * 8];
    acc0 = __builtin_amdgcn_mfma_f32_16x16x32_bf16(a0, bv, acc0, 0, 0, 0);
    acc1 = __builtin_amdgcn_mfma_f32_16x16x32_bf16(a1, bv, acc1, 0, 0, 0);
    __syncthreads();
  }
#pragma unroll
  for (int im = 0; im < 2; im++)
#pragma unroll
    for (int r = 0; r < 4; r++) {
      int row = m0 + w * 32 + im * 16 + q * 4 + r;
      int b = row >> 11, s = row & 2047;
      float v = (im == 0 ? acc0[r] : acc1[r]) * SCALE_ - (1.0f - mask[row]) * BIGNEG_;
      outl[((size_t)(b * 16 + mq)) * 2048 + s] = v;
    }
}

// ---------------- in-place softmax over rows of 2048 ----------------
__global__ __launch_bounds__(256) void k_softmax(float* __restrict__ logits) {
  __shared__ float red[8];
  int t = threadIdx.x;
  int lane = t & 63, w = t >> 6;
  float* lg = logits + (size_t)blockIdx.x * 2048;
  float4 a = ((const float4*)lg)[t];
  float4 b = ((const float4*)lg)[t + 256];
  float mx = fmaxf(fmaxf(fmaxf(a.x, a.y), fmaxf(a.z, a.w)),
                   fmaxf(fmaxf(b.x, b.y), fmaxf(b.z, b.w)));
#pragma unroll
  for (int off = 32; off > 0; off >>= 1) mx = fmaxf(mx, __shfl_down(mx, off, 64));
  if (lane == 0) red[w] = mx;
  __syncthreads();
  mx = fmaxf(fmaxf(red[0], red[1]), fmaxf(red[2], red[3]));
  float4 ea, eb;
  ea.x = expf(a.x - mx); ea.y = expf(a.y - mx); ea.z = expf(a.z - mx); ea.w = expf(a.w - mx);
  eb.x = expf(b.x - mx); eb.y = expf(b.y - mx); eb.z = expf(b.z - mx); eb.w = expf(b.w - mx);
  float ps = ea.x + ea.y + ea.z + ea.w + eb.x + eb.y + eb.z + eb.w;
#pragma unroll
  for (int off = 32; off > 0; off >>= 1) ps += __shfl_down(ps, off, 64);
  if (lane == 0) red[4 + w] = ps;
  __syncthreads();
  float inv = 1.0f / (red[4] + red[5] + red[6] + red[7]);
  ea.x *= inv; ea.y *= inv; ea.z *= inv; ea.w *= inv;
  eb.x *= inv; eb.y *= inv; eb.z *= inv; eb.w *= inv;
  ((float4*)lg)[t] = ea;
  ((float4*)lg)[t + 256] = eb;
}

// ---------------- chunked weighted pool, stage 1 ----------------
__global__ __launch_bounds__(256) void k_poolpart(
    const float* __restrict__ att,             // (B,16,2048) softmaxed
    const unsigned short* __restrict__ X,      // (B,2048,1024) bf16
    float* __restrict__ partial) {             // (B,64,1024) f32
  __shared__ float satt[32 * 16];
  int c = blockIdx.x, b = blockIdx.y;
  int t = threadIdx.x;
  for (int i = t; i < 512; i += 256) {
    int sl = i >> 4, h = i & 15;
    satt[i] = att[(((size_t)b * 16 + h) << 11) + c * 32 + sl];
  }
  __syncthreads();
  int h = t >> 4;
  const ushort4* xp = (const ushort4*)X + ((size_t)b * 2048 + c * 32) * 256 + t;
  float4 acc = {0.f, 0.f, 0.f, 0.f};
#pragma unroll 8
  for (int sl = 0; sl < 32; sl++) {
    float av = satt[sl * 16 + h];
    ushort4 xv = xp[sl * 256];
    acc.x += av * bf2f(xv.x);
    acc.y += av * bf2f(xv.y);
    acc.z += av * bf2f(xv.z);
    acc.w += av * bf2f(xv.w);
  }
  ((float4*)partial)[((size_t)b * 64 + c) * 256 + t] = acc;
}

// ---------------- chunked weighted pool, stage 2 ----------------
__global__ __launch_bounds__(256) void k_poolfin(
    const float* __restrict__ partial,         // (B,64,1024)
    const float* __restrict__ gmul,            // null or (B,1024)
    float* __restrict__ outp) {                // (B,1024)
  int oi = blockIdx.x * 256 + threadIdx.x;
  int b = oi >> 10;
  const float* pp = partial + (size_t)b * 64 * 1024 + (oi & 1023);
  float s = 0.f;
#pragma unroll 8
  for (int c = 0; c < 64; c++) s += pp[(size_t)c * 1024];
  if (gmul) s *= gmul[oi];
  outp[oi] = s;
}

// ---------------- WPb[b][n][k] = WPT[n][k] * gk[b][k] ----------------
__global__ __launch_bounds__(256) void k_wpb(
    const unsigned short* __restrict__ WPT,    // (1024,1024) bf16, N-major
    const float* __restrict__ gk,              // (B,1024)
    unsigned short* __restrict__ WPb) {        // (B,1024,1024) bf16
  int i = blockIdx.x * 256 + threadIdx.x;      // 2M threads, 4 halfs each
  int flat4 = i * 4;
  int b = flat4 >> 20;
  int rem = flat4 & 1048575;
  int k = rem & 1023;
  ushort4 wv = *(const ushort4*)&WPT[rem];
  float4 gv = *(const float4*)&gk[b * 1024 + k];
  ushort4 o;
  o.x = f2bf(bf2f(wv.x) * gv.x);
  o.y = f2bf(bf2f(wv.y) * gv.y);
  o.z = f2bf(bf2f(wv.z) * gv.z);
  o.w = f2bf(bf2f(wv.w) * gv.w);
  *(ushort4*)&WPb[flat4] = o;
}

extern "C" void kernel_launch(void* const* d_in, const int* in_sizes, int n_in,
                              void* d_out, int out_size, void* d_ws, size_t ws_size,
                              hipStream_t stream) {
  const float* Qseq  = (const float*)d_in[0];
  const float* Kseq  = (const float*)d_in[1];
  const float* Qmask = (const float*)d_in[2];
  const float* Kmask = (const float*)d_in[3];
  const float* WQ    = (const float*)d_in[4];
  const float* WK    = (const float*)d_in[5];
  const float* Wq    = (const float*)d_in[6];
  const float* Wk    = (const float*)d_in[7];
  const float* WP    = (const float*)d_in[8];
  float* out = (float*)d_out;

  const size_t SD = (size_t)B_ * S_ * D_;  // 16,777,216
  unsigned short* Qbf  = (unsigned short*)d_ws;
  unsigned short* Khbf = Qbf + SD;
  unsigned short* buf0 = Khbf + SD;           // conv staging; later partial(2MB)+WPb(16MB)
  unsigned short* WQT  = buf0 + SD;
  unsigned short* WKT  = WQT + (size_t)D_ * D_;
  unsigned short* WPT  = WKT + (size_t)D_ * D_;
  unsigned short* WqT  = WPT + (size_t)D_ * D_;
  unsigned short* WkT  = WqT + (size_t)H_ * D_;
  float* ql = (float*)(WkT + (size_t)H_ * D_);
  float* kl = ql + (size_t)B_ * H_ * S_;
  float* gq = kl + (size_t)B_ * H_ * S_;
  float* gk = gq + (size_t)B_ * D_;
  float* partial = (float*)buf0;                            // 2 MB
  unsigned short* WPb = buf0 + 2 * 1024 * 1024;             // 16 MB (after partial window)

  dim3 blk256(256);
  dim3 tblk(32, 8);
  int n4 = (int)(SD / 4);
  dim3 convGrid((n4 + 255) / 256);
  const int M = B_ * S_;  // 16384

  // weight conversions
  k_transpose3<<<dim3(32, 32, 3), tblk, 0, stream>>>(WQ, WQT, WK, WKT, WP, WPT, D_, D_);
  k_transpose2<<<dim3(1, 32, 2), tblk, 0, stream>>>(Wq, WqT, Wk, WkT, D_, H_);

  // GEMM1: Qbf = Q_seq @ WQ
  k_conv<<<convGrid, blk256, 0, stream>>>(Qseq, buf0, n4);
  k_gemm128<<<dim3(1024), blk256, 0, stream>>>(buf0, WQT, WQT, 1 << 30, 0,
                                               Qbf, (float*)nullptr,
                                               (const unsigned short*)nullptr, M, D_, D_, 8);
  // GEMM2: Khbf = K_seq @ WK
  k_conv<<<convGrid, blk256, 0, stream>>>(Kseq, buf0, n4);
  k_gemm128<<<dim3(1024), blk256, 0, stream>>>(buf0, WKT, WKT, 1 << 30, 0,
                                               Khbf, (float*)nullptr,
                                               (const unsigned short*)nullptr, M, D_, D_, 8);

  // q attention -> gq
  k_logits16<<<dim3(128), blk256, 0, stream>>>(Qbf, WqT, Qmask, ql, D_);
  k_softmax<<<dim3(128), blk256, 0, stream>>>(ql);
  k_poolpart<<<dim3(64, 8), blk256, 0, stream>>>(ql, Qbf, partial);
  k_poolfin<<<dim3(32), blk256, 0, stream>>>(partial, (const float*)nullptr, gq);

  // k attention (fused gather over head-mixed QK_flat) -> gk
  k_logits16g<<<dim3(128), blk256, 0, stream>>>(Khbf, WkT, gq, Kmask, kl);
  k_softmax<<<dim3(128), blk256, 0, stream>>>(kl);
  k_poolpart<<<dim3(64, 8), blk256, 0, stream>>>(kl, Khbf, partial);
  k_poolfin<<<dim3(32), blk256, 0, stream>>>(partial, gq, gk);

  // final: out = Qbf @ (WP .* gk[b]) + Qbf
  k_wpb<<<dim3(8192), blk256, 0, stream>>>(WPT, gk, WPb);
  k_gemm128<<<dim3(1024), blk256, 0, stream>>>(Qbf, WPb, WPb, 0, 1 << 20,
                                               (unsigned short*)nullptr, out, Qbf,
                                               M, D_, D_, 8);
}

// Round 4
// 438.074 us; speedup vs baseline: 1.6592x; 1.0446x over previous
//
#include <hip/hip_runtime.h>
#include <cstdint>
#include <cstddef>

// Fastformer on MI355X. R4 pipeline:
//  - transpose-convert weights
//  - k_conv2: bf16-convert Q_seq->buf0 and K_seq->Kstage(=d_out region) in ONE dispatch
//  - k_gemm128 fused dual: Qbf = Qstage@WQ  AND  Khbf = Kstage@WK (2048 blocks)
//    * LDS XOR swizzle: granule g stages global k-octet (g&7)^((g>>3)&7) -> conflict-free b128 reads
//  - q-logits (N=16 MFMA) -> softmax -> chunked pool -> gq
//  - k-logits fused head-mixing gather + gq folded into B-frag -> softmax -> pool -> gk
//  - WPb[b] = WP^T * gk[b,:] ; GEMM3: out = Qbf @ WPb(b) + Qbf

#define B_ 8
#define S_ 2048
#define H_ 16
#define D_ 1024
#define SCALE_ 0.125f
#define BIGNEG_ 1e8f

typedef __attribute__((ext_vector_type(8))) __bf16 bf16x8;
typedef __attribute__((ext_vector_type(4))) float f32x4;

__device__ __forceinline__ unsigned short f2bf(float f) {
  unsigned int u = __float_as_uint(f);
  u += 0x7FFFu + ((u >> 16) & 1u);          // round-to-nearest-even
  return (unsigned short)(u >> 16);
}
__device__ __forceinline__ float bf2f(unsigned short h) {
  return __uint_as_float(((unsigned int)h) << 16);
}

__device__ __forceinline__ void gll16(const void* g, void* l) {
  __builtin_amdgcn_global_load_lds(
      (__attribute__((address_space(1))) void*)(uintptr_t)g,
      (__attribute__((address_space(3))) void*)(uintptr_t)l,
      16, 0, 0);
}

// ---------------- dual elementwise f32 -> bf16 ----------------
__global__ __launch_bounds__(256) void k_conv2(
    const float* __restrict__ in0, unsigned short* __restrict__ out0,
    const float* __restrict__ in1, unsigned short* __restrict__ out1, int n4) {
  int i = blockIdx.x * 256 + threadIdx.x;
  const float* in = in0;
  unsigned short* out = out0;
  if (i >= n4) { i -= n4; in = in1; out = out1; }
  float4 v = ((const float4*)in)[i];
  ushort4 o;
  o.x = f2bf(v.x); o.y = f2bf(v.y); o.z = f2bf(v.z); o.w = f2bf(v.w);
  ((ushort4*)out)[i] = o;
}

// ---------------- transpose + convert, z selects among 3 (K,N)->(N,K) ----------------
__global__ __launch_bounds__(256) void k_transpose3(
    const float* __restrict__ s0, unsigned short* __restrict__ d0,
    const float* __restrict__ s1, unsigned short* __restrict__ d1,
    const float* __restrict__ s2, unsigned short* __restrict__ d2,
    int K, int N) {
  const float* src = blockIdx.z == 0 ? s0 : (blockIdx.z == 1 ? s1 : s2);
  unsigned short* dst = blockIdx.z == 0 ? d0 : (blockIdx.z == 1 ? d1 : d2);
  __shared__ float tile[32][33];
  int n0 = blockIdx.x * 32, k0 = blockIdx.y * 32;
  int tx = threadIdx.x, ty = threadIdx.y;  // (32,8)
#pragma unroll
  for (int i = 0; i < 4; i++) {
    int r = ty + i * 8;
    if (k0 + r < K && n0 + tx < N) tile[r][tx] = src[(size_t)(k0 + r) * N + n0 + tx];
  }
  __syncthreads();
#pragma unroll
  for (int i = 0; i < 4; i++) {
    int rn = ty + i * 8;
    if (n0 + rn < N && k0 + tx < K)
      dst[(size_t)(n0 + rn) * K + k0 + tx] = f2bf(tile[tx][rn]);
  }
}

__global__ __launch_bounds__(256) void k_transpose2(
    const float* __restrict__ s0, unsigned short* __restrict__ d0,
    const float* __restrict__ s1, unsigned short* __restrict__ d1,
    int K, int N) {
  const float* src = blockIdx.z == 0 ? s0 : s1;
  unsigned short* dst = blockIdx.z == 0 ? d0 : d1;
  __shared__ float tile[32][33];
  int n0 = blockIdx.x * 32, k0 = blockIdx.y * 32;
  int tx = threadIdx.x, ty = threadIdx.y;
#pragma unroll
  for (int i = 0; i < 4; i++) {
    int r = ty + i * 8;
    if (k0 + r < K && n0 + tx < N) tile[r][tx] = src[(size_t)(k0 + r) * N + n0 + tx];
  }
  __syncthreads();
#pragma unroll
  for (int i = 0; i < 4; i++) {
    int rn = ty + i * 8;
    if (n0 + rn < N && k0 + tx < K)
      dst[(size_t)(n0 + rn) * K + k0 + tx] = f2bf(tile[tx][rn]);
  }
}

// ---------------- 128x128 bf16 GEMM, BK=64, XOR-swizzled LDS ----------------
// mt < asplit: C = A @ BTa^T -> Cbf ; else (mt-=asplit): C = Aalt @ BTb^T -> Calt
// if bstride: BT += (mt>>4)*bstride (per-batch B). Cf/Res apply to first path only use.
__global__ __launch_bounds__(256) void k_gemm128(
    const unsigned short* __restrict__ A, const unsigned short* __restrict__ Aalt,
    int asplit,
    const unsigned short* __restrict__ BTa, const unsigned short* __restrict__ BTb,
    int bstride,
    unsigned short* __restrict__ Cbf, unsigned short* __restrict__ Calt,
    float* __restrict__ Cf, const unsigned short* __restrict__ Res,
    int N, int K, int ntiles) {
  __shared__ unsigned short lA[128 * 64];
  __shared__ unsigned short lB[128 * 64];
  int t = threadIdx.x;
  int mt = blockIdx.x / ntiles, nt = blockIdx.x - mt * ntiles;
  const unsigned short* BT = BTa;
  unsigned short* Cb = Cbf;
  if (mt >= asplit) { mt -= asplit; A = Aalt; BT = BTb; Cb = Calt; }
  if (bstride) BT += (size_t)(mt >> 4) * bstride;
  int m0 = mt * 128, n0 = nt * 128;
  int lane = t & 63, w = t >> 6;
  int wm = (w >> 1) * 64, wn = (w & 1) * 64;
  int mq = lane & 15, q = lane >> 4;

  f32x4 zero = {0.f, 0.f, 0.f, 0.f};
  f32x4 acc[4][4];
#pragma unroll
  for (int i = 0; i < 4; i++)
#pragma unroll
    for (int j = 0; j < 4; j++) acc[i][j] = zero;

  // staging: granule g = t + p*256; row = g>>3; stages global k-octet (g&7)^(row&7)
  // so that slot layout is conflict-free for b128 fragment reads.
  const unsigned short* gA[4];
  const unsigned short* gB[4];
  unsigned short* pA[4];
  unsigned short* pB[4];
#pragma unroll
  for (int p = 0; p < 4; p++) {
    int g = t + p * 256;
    int row = g >> 3, cg = (g & 7) ^ (row & 7);
    gA[p] = A + (size_t)(m0 + row) * K + cg * 8;
    gB[p] = BT + (size_t)(n0 + row) * K + cg * 8;
    pA[p] = &lA[g * 8];
    pB[p] = &lB[g * 8];
  }

  int xa = mq & 7;  // row&7 for all fragment rows this lane touches
  for (int k0 = 0; k0 < K; k0 += 64) {
#pragma unroll
    for (int p = 0; p < 4; p++) gll16(gA[p] + k0, pA[p]);
#pragma unroll
    for (int p = 0; p < 4; p++) gll16(gB[p] + k0, pB[p]);
    __syncthreads();
#pragma unroll
    for (int kk = 0; kk < 2; kk++) {
      int xo = ((kk * 4 + q) ^ xa) * 8;
      bf16x8 av[4], bv[4];
#pragma unroll
      for (int i = 0; i < 4; i++)
        av[i] = *(const bf16x8*)&lA[(wm + i * 16 + mq) * 64 + xo];
#pragma unroll
      for (int i = 0; i < 4; i++)
        bv[i] = *(const bf16x8*)&lB[(wn + i * 16 + mq) * 64 + xo];
#pragma unroll
      for (int i = 0; i < 4; i++)
#pragma unroll
        for (int j = 0; j < 4; j++)
          acc[i][j] = __builtin_amdgcn_mfma_f32_16x16x32_bf16(av[i], bv[j], acc[i][j], 0, 0, 0);
    }
    __syncthreads();
  }

#pragma unroll
  for (int i = 0; i < 4; i++)
#pragma unroll
    for (int j = 0; j < 4; j++)
#pragma unroll
      for (int r = 0; r < 4; r++) {
        int row = m0 + wm + i * 16 + q * 4 + r;
        int col = n0 + wn + j * 16 + mq;
        size_t o = (size_t)row * N + col;
        float v = acc[i][j][r];
        if (Res) v += bf2f(Res[o]);
        if (Cf) Cf[o] = v;
        if (Cb) Cb[o] = f2bf(v);
      }
}

// ---------------- skinny GEMM N=16: logits with scale+mask ----------------
__global__ __launch_bounds__(256) void k_logits16(
    const unsigned short* __restrict__ A,      // (B*S, K) bf16
    const unsigned short* __restrict__ BT16,   // (16, K) bf16
    const float* __restrict__ mask,            // (B*S) f32
    float* __restrict__ outl,                  // (B,16,S) f32
    int K) {
  __shared__ unsigned short lA[128 * 32];
  int t = threadIdx.x;
  int m0 = blockIdx.x * 128;
  int lane = t & 63, w = t >> 6;
  int mq = lane & 15, q = lane >> 4;
  f32x4 zero = {0.f, 0.f, 0.f, 0.f};
  f32x4 acc0 = zero, acc1 = zero;
  int f0 = t, f1 = t + 256;
  const unsigned short* gA0 = A + (size_t)(m0 + (f0 >> 2)) * K + (f0 & 3) * 8;
  const unsigned short* gA1 = A + (size_t)(m0 + (f1 >> 2)) * K + (f1 & 3) * 8;
  unsigned short* pA0 = &lA[f0 * 8];
  unsigned short* pA1 = &lA[f1 * 8];
  for (int k0 = 0; k0 < K; k0 += 32) {
    gll16(gA0 + k0, pA0);
    gll16(gA1 + k0, pA1);
    bf16x8 bv = *(const bf16x8*)&BT16[(size_t)mq * K + k0 + q * 8];
    __syncthreads();
    bf16x8 a0 = *(const bf16x8*)&lA[(w * 32 + mq) * 32 + q * 8];
    bf16x8 a1 = *(const bf16x8*)&lA[(w * 32 + 16 + mq) * 32 + q * 8];
    acc0 = __builtin_amdgcn_mfma_f32_16x16x32_bf16(a0, bv, acc0, 0, 0, 0);
    acc1 = __builtin_amdgcn_mfma_f32_16x16x32_bf16(a1, bv, acc1, 0, 0, 0);
    __syncthreads();
  }
#pragma unroll
  for (int im = 0; im < 2; im++)
#pragma unroll
    for (int r = 0; r < 4; r++) {
      int row = m0 + w * 32 + im * 16 + q * 4 + r;
      int b = row >> 11, s = row & 2047;
      float v = (im == 0 ? acc0[r] : acc1[r]) * SCALE_ - (1.0f - mask[row]) * BIGNEG_;
      outl[((size_t)(b * 16 + mq)) * 2048 + s] = v;
    }
}

// ---------------- k-logits with fused head-mixing gather + gq-scaled B ----------------
__global__ __launch_bounds__(256) void k_logits16g(
    const unsigned short* __restrict__ Khbf,   // (B,2048,1024) bf16
    const unsigned short* __restrict__ WkT,    // (16,1024) bf16
    const float* __restrict__ gq,              // (B,1024) f32
    const float* __restrict__ mask,            // (B*S) f32
    float* __restrict__ outl) {                // (B,16,S) f32
  __shared__ unsigned short lA[128 * 32];
  int t = threadIdx.x;
  int m0 = blockIdx.x * 128;
  int bb = m0 >> 11, h2 = (m0 >> 7) & 15;
  int lane = t & 63, w = t >> 6;
  int mq = lane & 15, q = lane >> 4;
  f32x4 zero = {0.f, 0.f, 0.f, 0.f};
  f32x4 acc0 = zero, acc1 = zero;
  int f0 = t, f1 = t + 256;
  int r0 = f0 >> 2, c0 = f0 & 3;
  int r1 = f1 >> 2, c1 = f1 & 3;
  const unsigned short* base = Khbf + (size_t)bb * 2048 * 1024 + h2 * 64;
  const float* gqb = gq + bb * 1024 + h2 * 64;
  unsigned short* pA0 = &lA[f0 * 8];
  unsigned short* pA1 = &lA[f1 * 8];
  for (int k0 = 0; k0 < 1024; k0 += 32) {
    int kc0 = k0 + c0 * 8, kc1 = k0 + c1 * 8;
    gll16(base + (size_t)(16 * r0 + (kc0 >> 6)) * 1024 + (kc0 & 63), pA0);
    gll16(base + (size_t)(16 * r1 + (kc1 >> 6)) * 1024 + (kc1 & 63), pA1);
    int kq = k0 + q * 8;
    bf16x8 wv = *(const bf16x8*)&WkT[(size_t)mq * 1024 + kq];
    float4 g0 = *(const float4*)&gqb[kq & 63];
    float4 g1 = *(const float4*)&gqb[(kq & 63) + 4];
    bf16x8 bv;
    bv[0] = (__bf16)((float)wv[0] * g0.x);
    bv[1] = (__bf16)((float)wv[1] * g0.y);
    bv[2] = (__bf16)((float)wv[2] * g0.z);
    bv[3] = (__bf16)((float)wv[3] * g0.w);
    bv[4] = (__bf16)((float)wv[4] * g1.x);
    bv[5] = (__bf16)((float)wv[5] * g1.y);
    bv[6] = (__bf16)((float)wv[6] * g1.z);
    bv[7] = (__bf16)((float)wv[7] * g1.w);
    __syncthreads();
    bf16x8 a0 = *(const bf16x8*)&lA[(w * 32 + mq) * 32 + q * 8];
    bf16x8 a1 = *(const bf16x8*)&lA[(w * 32 + 16 + mq) * 32 + q * 8];
    acc0 = __builtin_amdgcn_mfma_f32_16x16x32_bf16(a0, bv, acc0, 0, 0, 0);
    acc1 = __builtin_amdgcn_mfma_f32_16x16x32_bf16(a1, bv, acc1, 0, 0, 0);
    __syncthreads();
  }
#pragma unroll
  for (int im = 0; im < 2; im++)
#pragma unroll
    for (int r = 0; r < 4; r++) {
      int row = m0 + w * 32 + im * 16 + q * 4 + r;
      int b = row >> 11, s = row & 2047;
      float v = (im == 0 ? acc0[r] : acc1[r]) * SCALE_ - (1.0f - mask[row]) * BIGNEG_;
      outl[((size_t)(b * 16 + mq)) * 2048 + s] = v;
    }
}

// ---------------- in-place softmax over rows of 2048 ----------------
__global__ __launch_bounds__(256) void k_softmax(float* __restrict__ logits) {
  __shared__ float red[8];
  int t = threadIdx.x;
  int lane = t & 63, w = t >> 6;
  float* lg = logits + (size_t)blockIdx.x * 2048;
  float4 a = ((const float4*)lg)[t];
  float4 b = ((const float4*)lg)[t + 256];
  float mx = fmaxf(fmaxf(fmaxf(a.x, a.y), fmaxf(a.z, a.w)),
                   fmaxf(fmaxf(b.x, b.y), fmaxf(b.z, b.w)));
#pragma unroll
  for (int off = 32; off > 0; off >>= 1) mx = fmaxf(mx, __shfl_down(mx, off, 64));
  if (lane == 0) red[w] = mx;
  __syncthreads();
  mx = fmaxf(fmaxf(red[0], red[1]), fmaxf(red[2], red[3]));
  float4 ea, eb;
  ea.x = expf(a.x - mx); ea.y = expf(a.y - mx); ea.z = expf(a.z - mx); ea.w = expf(a.w - mx);
  eb.x = expf(b.x - mx); eb.y = expf(b.y - mx); eb.z = expf(b.z - mx); eb.w = expf(b.w - mx);
  float ps = ea.x + ea.y + ea.z + ea.w + eb.x + eb.y + eb.z + eb.w;
#pragma unroll
  for (int off = 32; off > 0; off >>= 1) ps += __shfl_down(ps, off, 64);
  if (lane == 0) red[4 + w] = ps;
  __syncthreads();
  float inv = 1.0f / (red[4] + red[5] + red[6] + red[7]);
  ea.x *= inv; ea.y *= inv; ea.z *= inv; ea.w *= inv;
  eb.x *= inv; eb.y *= inv; eb.z *= inv; eb.w *= inv;
  ((float4*)lg)[t] = ea;
  ((float4*)lg)[t + 256] = eb;
}

// ---------------- chunked weighted pool, stage 1 ----------------
__global__ __launch_bounds__(256) void k_poolpart(
    const float* __restrict__ att,             // (B,16,2048) softmaxed
    const unsigned short* __restrict__ X,      // (B,2048,1024) bf16
    float* __restrict__ partial) {             // (B,64,1024) f32
  __shared__ float satt[32 * 16];
  int c = blockIdx.x, b = blockIdx.y;
  int t = threadIdx.x;
  for (int i = t; i < 512; i += 256) {
    int sl = i >> 4, h = i & 15;
    satt[i] = att[(((size_t)b * 16 + h) << 11) + c * 32 + sl];
  }
  __syncthreads();
  int h = t >> 4;
  const ushort4* xp = (const ushort4*)X + ((size_t)b * 2048 + c * 32) * 256 + t;
  float4 acc = {0.f, 0.f, 0.f, 0.f};
#pragma unroll 8
  for (int sl = 0; sl < 32; sl++) {
    float av = satt[sl * 16 + h];
    ushort4 xv = xp[sl * 256];
    acc.x += av * bf2f(xv.x);
    acc.y += av * bf2f(xv.y);
    acc.z += av * bf2f(xv.z);
    acc.w += av * bf2f(xv.w);
  }
  ((float4*)partial)[((size_t)b * 64 + c) * 256 + t] = acc;
}

// ---------------- chunked weighted pool, stage 2 ----------------
__global__ __launch_bounds__(256) void k_poolfin(
    const float* __restrict__ partial,         // (B,64,1024)
    const float* __restrict__ gmul,            // null or (B,1024)
    float* __restrict__ outp) {                // (B,1024)
  int oi = blockIdx.x * 256 + threadIdx.x;
  int b = oi >> 10;
  const float* pp = partial + (size_t)b * 64 * 1024 + (oi & 1023);
  float s = 0.f;
#pragma unroll 8
  for (int c = 0; c < 64; c++) s += pp[(size_t)c * 1024];
  if (gmul) s *= gmul[oi];
  outp[oi] = s;
}

// ---------------- WPb[b][n][k] = WPT[n][k] * gk[b][k] ----------------
__global__ __launch_bounds__(256) void k_wpb(
    const unsigned short* __restrict__ WPT,    // (1024,1024) bf16, N-major
    const float* __restrict__ gk,              // (B,1024)
    unsigned short* __restrict__ WPb) {        // (B,1024,1024) bf16
  int i = blockIdx.x * 256 + threadIdx.x;
  int flat4 = i * 4;
  int b = flat4 >> 20;
  int rem = flat4 & 1048575;
  int k = rem & 1023;
  ushort4 wv = *(const ushort4*)&WPT[rem];
  float4 gv = *(const float4*)&gk[b * 1024 + k];
  ushort4 o;
  o.x = f2bf(bf2f(wv.x) * gv.x);
  o.y = f2bf(bf2f(wv.y) * gv.y);
  o.z = f2bf(bf2f(wv.z) * gv.z);
  o.w = f2bf(bf2f(wv.w) * gv.w);
  *(ushort4*)&WPb[flat4] = o;
}

extern "C" void kernel_launch(void* const* d_in, const int* in_sizes, int n_in,
                              void* d_out, int out_size, void* d_ws, size_t ws_size,
                              hipStream_t stream) {
  const float* Qseq  = (const float*)d_in[0];
  const float* Kseq  = (const float*)d_in[1];
  const float* Qmask = (const float*)d_in[2];
  const float* Kmask = (const float*)d_in[3];
  const float* WQ    = (const float*)d_in[4];
  const float* WK    = (const float*)d_in[5];
  const float* Wq    = (const float*)d_in[6];
  const float* Wk    = (const float*)d_in[7];
  const float* WP    = (const float*)d_in[8];
  float* out = (float*)d_out;

  const size_t SD = (size_t)B_ * S_ * D_;  // 16,777,216
  unsigned short* Qbf  = (unsigned short*)d_ws;
  unsigned short* Khbf = Qbf + SD;
  unsigned short* buf0 = Khbf + SD;           // Q conv staging; later partial(2MB)+WPb(16MB)
  unsigned short* WQT  = buf0 + SD;
  unsigned short* WKT  = WQT + (size_t)D_ * D_;
  unsigned short* WPT  = WKT + (size_t)D_ * D_;
  unsigned short* WqT  = WPT + (size_t)D_ * D_;
  unsigned short* WkT  = WqT + (size_t)H_ * D_;
  float* ql = (float*)(WkT + (size_t)H_ * D_);
  float* kl = ql + (size_t)B_ * H_ * S_;
  float* gq = kl + (size_t)B_ * H_ * S_;
  float* gk = gq + (size_t)B_ * D_;
  float* partial = (float*)buf0;                            // 2 MB
  unsigned short* WPb = buf0 + 2 * 1024 * 1024;             // 16 MB
  unsigned short* Kstage = (unsigned short*)d_out;          // 32 MB of the 64 MB f32 out buffer

  dim3 blk256(256);
  dim3 tblk(32, 8);
  int n4 = (int)(SD / 4);
  const int M = B_ * S_;  // 16384

  // weight conversions
  k_transpose3<<<dim3(32, 32, 3), tblk, 0, stream>>>(WQ, WQT, WK, WKT, WP, WPT, D_, D_);
  k_transpose2<<<dim3(1, 32, 2), tblk, 0, stream>>>(Wq, WqT, Wk, WkT, D_, H_);

  // convert both activations in one dispatch
  k_conv2<<<dim3(2 * ((n4 + 255) / 256)), blk256, 0, stream>>>(Qseq, buf0, Kseq, Kstage, n4);

  // fused GEMM1+GEMM2: Qbf = Qstage@WQ ; Khbf = Kstage@WK
  k_gemm128<<<dim3(2048), blk256, 0, stream>>>(buf0, Kstage, 128, WQT, WKT, 0,
                                               Qbf, Khbf, (float*)nullptr,
                                               (const unsigned short*)nullptr, D_, D_, 8);

  // q attention -> gq
  k_logits16<<<dim3(128), blk256, 0, stream>>>(Qbf, WqT, Qmask, ql, D_);
  k_softmax<<<dim3(128), blk256, 0, stream>>>(ql);
  k_poolpart<<<dim3(64, 8), blk256, 0, stream>>>(ql, Qbf, partial);
  k_poolfin<<<dim3(32), blk256, 0, stream>>>(partial, (const float*)nullptr, gq);

  // k attention (fused gather over head-mixed QK_flat) -> gk
  k_logits16g<<<dim3(128), blk256, 0, stream>>>(Khbf, WkT, gq, Kmask, kl);
  k_softmax<<<dim3(128), blk256, 0, stream>>>(kl);
  k_poolpart<<<dim3(64, 8), blk256, 0, stream>>>(kl, Khbf, partial);
  k_poolfin<<<dim3(32), blk256, 0, stream>>>(partial, gq, gk);

  // final: out = Qbf @ (WP .* gk[b]) + Qbf   (overwrites Kstage region — no longer read)
  k_wpb<<<dim3(8192), blk256, 0, stream>>>(WPT, gk, WPb);
  k_gemm128<<<dim3(1024), blk256, 0, stream>>>(Qbf, Qbf, 1 << 30, WPb, WPb, 1 << 20,
                                               (unsigned short*)nullptr, (unsigned short*)nullptr,
                                               out, Qbf, D_, D_, 8);
}